// Round 14
// baseline (53.928 us; speedup 1.0000x reference)
//
#include <hip/hip_runtime.h>

typedef float v2f __attribute__((ext_vector_type(2)));

#define SCHED_FENCE() __builtin_amdgcn_sched_barrier(0)

// compile-time DPP move. bound_ctrl=true: OOB/disabled source lanes read 0.
// NOTE: execute with source lanes ACTIVE (EXEC-disabled sources read 0).
template<int CTRL>
__device__ __forceinline__ float dppmov(float x) {
    return __builtin_bit_cast(float,
        __builtin_amdgcn_update_dpp(0, __builtin_bit_cast(int, x),
                                    CTRL, 0xf, 0xf, true));
}
#define DPP_XOR1  0xB1   // quad_perm [1,0,3,2]
#define DPP_XOR2  0x4E   // quad_perm [2,3,0,1]
#define DPP_XOR8  0x128  // row_ror:8 == lane^8 within 16-lane rows
#define DPP_SHR(d) (0x110 | (d))

// packed penetration: row sphere r vs column spheres of links (j, j+1)
// packed as v2f {j, j+1}. m[i] folds with v_max3; m[j], m[j+1] plain max.
__device__ __forceinline__ void pen2j(const float4& r,
                                      v2f px, v2f py, v2f pz, v2f pw,
                                      float& mi, float& mj1, float& mj2)
{
    v2f dx = px - r.x;
    v2f dy = py - r.y;
    v2f dz = pz - r.z;
    v2f d2 = dx * dx;
    d2 = __builtin_elementwise_fma(dy, dy, d2);
    d2 = __builtin_elementwise_fma(dz, dz, d2);
    v2f pen = (pw + r.w) - (v2f){__builtin_amdgcn_sqrtf(d2.x),
                                 __builtin_amdgcn_sqrtf(d2.y)};
    mi  = fmaxf(fmaxf(mi, pen.x), pen.y);   // v_max3_f32
    mj1 = fmaxf(mj1, pen.x);
    mj2 = fmaxf(mj2, pen.y);
}

// second column (j+1) of a pack only (the i = j-1 boundary row)
__device__ __forceinline__ void pen1h(const float4& r,
                                      v2f px, v2f py, v2f pz, v2f pw,
                                      float& mi, float& mj)
{
    float dx = px.y - r.x, dy = py.y - r.y, dz = pz.y - r.z;
    float d2 = fmaf(dx, dx, fmaf(dy, dy, dz * dz));
    float p  = pw.y + r.w - __builtin_amdgcn_sqrtf(d2);
    mi = fmaxf(mi, p);
    mj = fmaxf(mj, p);
}

// ---------------------------------------------------------------------------
// ONE batch per wave, (256,8) cap targeting 8 waves/SIMD.
// Fence placement experiment (R12 none -> spill 61us; R13 all -> fits but
// over-serialized 23.7us): ONE fence at the FK->pair boundary blocks the
// cross-phase ds_read hoist that exploded liveness in R12, while leaving the
// pair phase free for the compiler's own software pipelining.
//  - branchless DPP scan; padded LDS (stride 9); named scalars only.
//  - pair: 7 adjacent-link v2f packs, two live at a time, 4 unfenced sweeps.
//  - reduce: named-scalar log-fold, 13 DPP + 4 shfl.
// ---------------------------------------------------------------------------
__global__ __launch_bounds__(256, 8) void fused_kernel(
    const float* __restrict__ q,        // [B,16]
    const float* __restrict__ frot,     // [16,3,3]
    const float* __restrict__ ftrans,   // [16,3]
    const float* __restrict__ axes,     // [16,3]
    const float* __restrict__ spheres,  // [16,8,4]
    float* __restrict__ out,            // [B,16]
    int B)
{
    __shared__ float4 sph[4][16 * 9];
    const int t    = threadIdx.x;
    const int w    = t >> 6;
    const int lane = t & 63;
    int b = blockIdx.x * 4 + w;
    const bool alive = (b < B);
    if (!alive) b = B - 1;

    const int l = lane & 15;            // link this lane owns in FK phase
    const int g = lane >> 4;            // sphere-group (2 spheres each)

    const float qv = q[(size_t)b * 16 + l];
    const float s = __sinf(qv), c = __cosf(qv), oc = 1.0f - c;
    const float ax = axes[3*l+0], ay = axes[3*l+1], az = axes[3*l+2];

    // ---- local joint transform R = F * J(axis,q), row-wise (F rows die fast)
    float R00,R01,R02,R10,R11,R12,R20,R21,R22;
    #define BUILD_ROW(Ra, Rb, Rc, base)                                         \
    {                                                                           \
        float f0 = frot[base+0], f1 = frot[base+1], f2 = frot[base+2];          \
        float u0 = fmaf(f1,az, -f2*ay);                                         \
        float u1 = fmaf(f2,ax, -f0*az);                                         \
        float u2 = fmaf(f0,ay, -f1*ax);                                         \
        float v0 = fmaf(u1,az, -u2*ay);                                         \
        float v1 = fmaf(u2,ax, -u0*az);                                         \
        float v2 = fmaf(u0,ay, -u1*ax);                                         \
        Ra = fmaf(oc,v0, fmaf(s,u0, f0));                                       \
        Rb = fmaf(oc,v1, fmaf(s,u1, f1));                                       \
        Rc = fmaf(oc,v2, fmaf(s,u2, f2));                                       \
    }
    BUILD_ROW(R00,R01,R02, 9*l+0)
    BUILD_ROW(R10,R11,R12, 9*l+3)
    BUILD_ROW(R20,R21,R22, 9*l+6)
    #undef BUILD_ROW
    float t0 = ftrans[3*l+0], t1 = ftrans[3*l+1], t2 = ftrans[3*l+2];
    SCHED_FENCE();

    // ---- branchless Kogge-Stone prefix product (ALL dpp above "divergence")
    #define SCAN_STEP(D, CTRL)                                                  \
    {                                                                           \
        float P00 = dppmov<CTRL>(R00), P01 = dppmov<CTRL>(R01), P02 = dppmov<CTRL>(R02); \
        float P10 = dppmov<CTRL>(R10), P11 = dppmov<CTRL>(R11), P12 = dppmov<CTRL>(R12); \
        float P20 = dppmov<CTRL>(R20), P21 = dppmov<CTRL>(R21), P22 = dppmov<CTRL>(R22); \
        float pt0 = dppmov<CTRL>(t0),  pt1 = dppmov<CTRL>(t1),  pt2 = dppmov<CTRL>(t2);  \
        const bool lo = (l < (D));                                              \
        P00 = lo ? 1.0f : P00;                                                  \
        P11 = lo ? 1.0f : P11;                                                  \
        P22 = lo ? 1.0f : P22;                                                  \
        {                                                                       \
            float n00 = fmaf(P00,R00, fmaf(P01,R10, P02*R20));                  \
            float n01 = fmaf(P00,R01, fmaf(P01,R11, P02*R21));                  \
            float n02 = fmaf(P00,R02, fmaf(P01,R12, P02*R22));                  \
            float n10 = fmaf(P10,R00, fmaf(P11,R10, P12*R20));                  \
            float n11 = fmaf(P10,R01, fmaf(P11,R11, P12*R21));                  \
            float n12 = fmaf(P10,R02, fmaf(P11,R12, P12*R22));                  \
            float n20 = fmaf(P20,R00, fmaf(P21,R10, P22*R20));                  \
            float n21 = fmaf(P20,R01, fmaf(P21,R11, P22*R21));                  \
            float n22 = fmaf(P20,R02, fmaf(P21,R12, P22*R22));                  \
            float nt0 = fmaf(P00,t0, fmaf(P01,t1, fmaf(P02,t2, pt0)));          \
            float nt1 = fmaf(P10,t0, fmaf(P11,t1, fmaf(P12,t2, pt1)));          \
            float nt2 = fmaf(P20,t0, fmaf(P21,t1, fmaf(P22,t2, pt2)));          \
            R00=n00; R01=n01; R02=n02;                                          \
            R10=n10; R11=n11; R12=n12;                                          \
            R20=n20; R21=n21; R22=n22;                                          \
            t0=nt0; t1=nt1; t2=nt2;                                             \
        }                                                                       \
    }
    SCAN_STEP(1, DPP_SHR(1))
    SCAN_STEP(2, DPP_SHR(2))
    SCAN_STEP(4, DPP_SHR(4))
    SCAN_STEP(8, DPP_SHR(8))
    #undef SCAN_STEP

    // ---- transform this lane's 2 spheres of link l into padded LDS
    #pragma unroll
    for (int k = 0; k < 2; ++k) {
        const int sp = g * 2 + k;
        float4 cs = reinterpret_cast<const float4*>(spheres)[l*8 + sp];
        float wx = fmaf(R00,cs.x, fmaf(R01,cs.y, fmaf(R02,cs.z, t0)));
        float wy = fmaf(R10,cs.x, fmaf(R11,cs.y, fmaf(R12,cs.z, t1)));
        float wz = fmaf(R20,cs.x, fmaf(R21,cs.y, fmaf(R22,cs.z, t2)));
        sph[w][l*9 + sp] = make_float4(wx, wy, wz, cs.w);
    }
    // wave-private LDS slice: drain this wave's writes, no block barrier
    asm volatile("s_waitcnt lgkmcnt(0)" ::: "memory");
    // THE fence: forbid pair-phase ds_reads from hoisting above this point
    // (R12's liveness explosion). Pair phase below is left unfenced.
    SCHED_FENCE();

    // ---- pairwise penetration (64 lanes on one batch), named scalars only
    const float4* S  = sph[w];
    const float*  Sf = reinterpret_cast<const float*>(S);
    const int sr = lane >> 3;      // row sphere 0..7
    const int sc = lane & 7;       // col sphere 0..7
    const float4* Srow = S + sr;   // row i at Srow[i*9]
    const float*  Scol = Sf + sc*4;

    float m0=-100.f,m1=-100.f,m2=-100.f,m3=-100.f,m4=-100.f,m5=-100.f,
          m6=-100.f,m7=-100.f,m8=-100.f,m9=-100.f,m10=-100.f,m11=-100.f,
          m12=-100.f,m13=-100.f,m14=-100.f,m15=-100.f;

    v2f Ax,Ay,Az,Aw, Bx,By,Bz,Bw;

    // fill pack P = column spheres sc of links (j, j+1): paired scalar LDS
    // loads 36 dwords apart (-> ds_read2_b32), born packed.
    #define FILLP(Px,Py,Pz,Pw, j)                                               \
    {                                                                           \
        Px = (v2f){Scol[(j)*36+0], Scol[(j)*36+36]};                            \
        Py = (v2f){Scol[(j)*36+1], Scol[(j)*36+37]};                            \
        Pz = (v2f){Scol[(j)*36+2], Scol[(j)*36+38]};                            \
        Pw = (v2f){Scol[(j)*36+3], Scol[(j)*36+39]};                            \
    }

    // sweep 1: packs A=(2,3), B=(4,5); rows 0..3
    FILLP(Ax,Ay,Az,Aw, 2)
    FILLP(Bx,By,Bz,Bw, 4)
    { float4 r = Srow[0*9]; pen2j(r,Ax,Ay,Az,Aw, m0,m2,m3); pen2j(r,Bx,By,Bz,Bw, m0,m4,m5); }
    { float4 r = Srow[1*9]; pen1h(r,Ax,Ay,Az,Aw, m1,m3);    pen2j(r,Bx,By,Bz,Bw, m1,m4,m5); }
    { float4 r = Srow[2*9]; pen2j(r,Bx,By,Bz,Bw, m2,m4,m5); }
    { float4 r = Srow[3*9]; pen1h(r,Bx,By,Bz,Bw, m3,m5); }

    // sweep 2: packs A=(6,7), B=(8,9); rows 0..7
    FILLP(Ax,Ay,Az,Aw, 6)
    FILLP(Bx,By,Bz,Bw, 8)
    { float4 r = Srow[0*9]; pen2j(r,Ax,Ay,Az,Aw, m0,m6,m7); pen2j(r,Bx,By,Bz,Bw, m0,m8,m9); }
    { float4 r = Srow[1*9]; pen2j(r,Ax,Ay,Az,Aw, m1,m6,m7); pen2j(r,Bx,By,Bz,Bw, m1,m8,m9); }
    { float4 r = Srow[2*9]; pen2j(r,Ax,Ay,Az,Aw, m2,m6,m7); pen2j(r,Bx,By,Bz,Bw, m2,m8,m9); }
    { float4 r = Srow[3*9]; pen2j(r,Ax,Ay,Az,Aw, m3,m6,m7); pen2j(r,Bx,By,Bz,Bw, m3,m8,m9); }
    { float4 r = Srow[4*9]; pen2j(r,Ax,Ay,Az,Aw, m4,m6,m7); pen2j(r,Bx,By,Bz,Bw, m4,m8,m9); }
    { float4 r = Srow[5*9]; pen1h(r,Ax,Ay,Az,Aw, m5,m7);    pen2j(r,Bx,By,Bz,Bw, m5,m8,m9); }
    { float4 r = Srow[6*9]; pen2j(r,Bx,By,Bz,Bw, m6,m8,m9); }
    { float4 r = Srow[7*9]; pen1h(r,Bx,By,Bz,Bw, m7,m9); }

    // sweep 3: packs A=(10,11), B=(12,13); rows 0..11
    FILLP(Ax,Ay,Az,Aw, 10)
    FILLP(Bx,By,Bz,Bw, 12)
    { float4 r = Srow[0*9];  pen2j(r,Ax,Ay,Az,Aw, m0,m10,m11); pen2j(r,Bx,By,Bz,Bw, m0,m12,m13); }
    { float4 r = Srow[1*9];  pen2j(r,Ax,Ay,Az,Aw, m1,m10,m11); pen2j(r,Bx,By,Bz,Bw, m1,m12,m13); }
    { float4 r = Srow[2*9];  pen2j(r,Ax,Ay,Az,Aw, m2,m10,m11); pen2j(r,Bx,By,Bz,Bw, m2,m12,m13); }
    { float4 r = Srow[3*9];  pen2j(r,Ax,Ay,Az,Aw, m3,m10,m11); pen2j(r,Bx,By,Bz,Bw, m3,m12,m13); }
    { float4 r = Srow[4*9];  pen2j(r,Ax,Ay,Az,Aw, m4,m10,m11); pen2j(r,Bx,By,Bz,Bw, m4,m12,m13); }
    { float4 r = Srow[5*9];  pen2j(r,Ax,Ay,Az,Aw, m5,m10,m11); pen2j(r,Bx,By,Bz,Bw, m5,m12,m13); }
    { float4 r = Srow[6*9];  pen2j(r,Ax,Ay,Az,Aw, m6,m10,m11); pen2j(r,Bx,By,Bz,Bw, m6,m12,m13); }
    { float4 r = Srow[7*9];  pen2j(r,Ax,Ay,Az,Aw, m7,m10,m11); pen2j(r,Bx,By,Bz,Bw, m7,m12,m13); }
    { float4 r = Srow[8*9];  pen2j(r,Ax,Ay,Az,Aw, m8,m10,m11); pen2j(r,Bx,By,Bz,Bw, m8,m12,m13); }
    { float4 r = Srow[9*9];  pen1h(r,Ax,Ay,Az,Aw, m9,m11);     pen2j(r,Bx,By,Bz,Bw, m9,m12,m13); }
    { float4 r = Srow[10*9]; pen2j(r,Bx,By,Bz,Bw, m10,m12,m13); }
    { float4 r = Srow[11*9]; pen1h(r,Bx,By,Bz,Bw, m11,m13); }

    // sweep 4: pack A=(14,15); rows 0..13
    FILLP(Ax,Ay,Az,Aw, 14)
    { float4 r = Srow[0*9];  pen2j(r,Ax,Ay,Az,Aw, m0,m14,m15); }
    { float4 r = Srow[1*9];  pen2j(r,Ax,Ay,Az,Aw, m1,m14,m15); }
    { float4 r = Srow[2*9];  pen2j(r,Ax,Ay,Az,Aw, m2,m14,m15); }
    { float4 r = Srow[3*9];  pen2j(r,Ax,Ay,Az,Aw, m3,m14,m15); }
    { float4 r = Srow[4*9];  pen2j(r,Ax,Ay,Az,Aw, m4,m14,m15); }
    { float4 r = Srow[5*9];  pen2j(r,Ax,Ay,Az,Aw, m5,m14,m15); }
    { float4 r = Srow[6*9];  pen2j(r,Ax,Ay,Az,Aw, m6,m14,m15); }
    { float4 r = Srow[7*9];  pen2j(r,Ax,Ay,Az,Aw, m7,m14,m15); }
    { float4 r = Srow[8*9];  pen2j(r,Ax,Ay,Az,Aw, m8,m14,m15); }
    { float4 r = Srow[9*9];  pen2j(r,Ax,Ay,Az,Aw, m9,m14,m15); }
    { float4 r = Srow[10*9]; pen2j(r,Ax,Ay,Az,Aw, m10,m14,m15); }
    { float4 r = Srow[11*9]; pen2j(r,Ax,Ay,Az,Aw, m11,m14,m15); }
    { float4 r = Srow[12*9]; pen2j(r,Ax,Ay,Az,Aw, m12,m14,m15); }
    { float4 r = Srow[13*9]; pen1h(r,Ax,Ay,Az,Aw, m13,m15); }
    #undef FILLP

    // ---- log-fold wave reduction, named scalars (13 DPP + 4 shfl)
    {
        const int bit0 = lane & 1;
        #define F1(A,C) { float s_ = bit0 ? A : C; float r_ = dppmov<DPP_XOR1>(s_); A = fmaxf(bit0 ? C : A, r_); }
        F1(m0,m8) F1(m1,m9) F1(m2,m10) F1(m3,m11) F1(m4,m12) F1(m5,m13) F1(m6,m14) F1(m7,m15)
        #undef F1
        const int bit1 = (lane >> 1) & 1;
        #define F2(A,C) { float s_ = bit1 ? A : C; float r_ = dppmov<DPP_XOR2>(s_); A = fmaxf(bit1 ? C : A, r_); }
        F2(m0,m4) F2(m1,m5) F2(m2,m6) F2(m3,m7)
        #undef F2
        const int bit2 = (lane >> 2) & 1;
        #define F4(A,C) { float s_ = bit2 ? A : C; float r_ = __shfl_xor(s_, 4, 64); A = fmaxf(bit2 ? C : A, r_); }
        F4(m0,m2) F4(m1,m3)
        #undef F4
        const int bit3 = (lane >> 3) & 1;
        { float s_ = bit3 ? m0 : m1; float r_ = dppmov<DPP_XOR8>(s_); m0 = fmaxf(bit3 ? m1 : m0, r_); }
        m0 = fmaxf(m0, __shfl_xor(m0, 16, 64));
        m0 = fmaxf(m0, __shfl_xor(m0, 32, 64));
    }

    if (alive && lane < 16) {
        // link index = bit-reversal of lane's low 4 bits
        int k = ((lane & 1) << 3) | ((lane & 2) << 1) | ((lane & 4) >> 1) | ((lane & 8) >> 3);
        out[(size_t)b * 16 + k] = m0;
    }
}

// ---------------------------------------------------------------------------
extern "C" void kernel_launch(void* const* d_in, const int* in_sizes, int n_in,
                              void* d_out, int out_size, void* d_ws, size_t ws_size,
                              hipStream_t stream) {
    const float* q      = (const float*)d_in[0];
    const float* frot   = (const float*)d_in[1];
    const float* ftrans = (const float*)d_in[2];
    const float* axes   = (const float*)d_in[3];
    const float* sphere = (const float*)d_in[4];
    float* out = (float*)d_out;

    const int B = in_sizes[0] / 16;
    const int blocks = (B + 3) / 4;     // 1 batch per wave, 4 per block
    fused_kernel<<<dim3(blocks), dim3(256), 0, stream>>>(
        q, frot, ftrans, axes, sphere, out, B);
}

// Round 15
// 34.214 us; speedup vs baseline: 1.5762x; 1.5762x over previous
//
#include <hip/hip_runtime.h>

typedef float v2f __attribute__((ext_vector_type(2)));

#define SCHED_FENCE() __builtin_amdgcn_sched_barrier(0)

// compile-time DPP move. bound_ctrl=true: OOB/disabled source lanes read 0.
template<int CTRL>
__device__ __forceinline__ float dppmov(float x) {
    return __builtin_bit_cast(float,
        __builtin_amdgcn_update_dpp(0, __builtin_bit_cast(int, x),
                                    CTRL, 0xf, 0xf, true));
}
#define DPP_XOR1  0xB1   // quad_perm [1,0,3,2]
#define DPP_XOR2  0x4E   // quad_perm [2,3,0,1]
#define DPP_XOR8  0x128  // row_ror:8 == lane^8 within 16-lane rows
#define DPP_SHR(d) (0x110 | (d))

// ---------------------------------------------------------------------------
// K1: forward kinematics. TWO batches per wave (R11's proven structure).
// Writes world spheres (x,y,z,r) to ws[b*128 + link*8 + sp]. 128-reg tier.
// ---------------------------------------------------------------------------
__global__ __launch_bounds__(256, 4) void fk_kernel(
    const float* __restrict__ q,        // [B,16]
    const float* __restrict__ frot,     // [16,3,3]
    const float* __restrict__ ftrans,   // [16,3]
    const float* __restrict__ axes,     // [16,3]
    const float* __restrict__ spheres,  // [16,8,4]
    float4* __restrict__ ws,            // [B,128]
    int B)
{
    const int t    = threadIdx.x;
    const int w    = t >> 6;
    const int lane = t & 63;
    const int h    = lane >> 5;
    int b = blockIdx.x * 8 + w * 2 + h;
    const bool alive = (b < B);
    if (!alive) b = B - 1;

    const int l = lane & 15;
    const int g = (lane >> 4) & 1;

    const float qv = q[(size_t)b * 16 + l];
    const float s = __sinf(qv), c = __cosf(qv), oc = 1.0f - c;
    const float ax = axes[3*l+0], ay = axes[3*l+1], az = axes[3*l+2];

    const float F00=frot[9*l+0], F01=frot[9*l+1], F02=frot[9*l+2];
    const float F10=frot[9*l+3], F11=frot[9*l+4], F12=frot[9*l+5];
    const float F20=frot[9*l+6], F21=frot[9*l+7], F22=frot[9*l+8];

    float R00,R01,R02,R10,R11,R12,R20,R21,R22;
    {
        float u0 = fmaf(F01,az, -F02*ay);
        float u1 = fmaf(F02,ax, -F00*az);
        float u2 = fmaf(F00,ay, -F01*ax);
        float v0 = fmaf(u1,az, -u2*ay);
        float v1 = fmaf(u2,ax, -u0*az);
        float v2 = fmaf(u0,ay, -u1*ax);
        R00 = fmaf(oc,v0, fmaf(s,u0, F00));
        R01 = fmaf(oc,v1, fmaf(s,u1, F01));
        R02 = fmaf(oc,v2, fmaf(s,u2, F02));

        u0 = fmaf(F11,az, -F12*ay);
        u1 = fmaf(F12,ax, -F10*az);
        u2 = fmaf(F10,ay, -F11*ax);
        v0 = fmaf(u1,az, -u2*ay);
        v1 = fmaf(u2,ax, -u0*az);
        v2 = fmaf(u0,ay, -u1*ax);
        R10 = fmaf(oc,v0, fmaf(s,u0, F10));
        R11 = fmaf(oc,v1, fmaf(s,u1, F11));
        R12 = fmaf(oc,v2, fmaf(s,u2, F12));

        u0 = fmaf(F21,az, -F22*ay);
        u1 = fmaf(F22,ax, -F20*az);
        u2 = fmaf(F20,ay, -F21*ax);
        v0 = fmaf(u1,az, -u2*ay);
        v1 = fmaf(u2,ax, -u0*az);
        v2 = fmaf(u0,ay, -u1*ax);
        R20 = fmaf(oc,v0, fmaf(s,u0, F20));
        R21 = fmaf(oc,v1, fmaf(s,u1, F21));
        R22 = fmaf(oc,v2, fmaf(s,u2, F22));
    }
    float t0 = ftrans[3*l+0], t1 = ftrans[3*l+1], t2 = ftrans[3*l+2];

    // branchless Kogge-Stone prefix product (bound_ctrl zeros + forced I diag)
    #define SCAN_STEP(D, CTRL)                                                  \
    {                                                                           \
        float P00 = dppmov<CTRL>(R00), P01 = dppmov<CTRL>(R01), P02 = dppmov<CTRL>(R02); \
        float P10 = dppmov<CTRL>(R10), P11 = dppmov<CTRL>(R11), P12 = dppmov<CTRL>(R12); \
        float P20 = dppmov<CTRL>(R20), P21 = dppmov<CTRL>(R21), P22 = dppmov<CTRL>(R22); \
        float pt0 = dppmov<CTRL>(t0),  pt1 = dppmov<CTRL>(t1),  pt2 = dppmov<CTRL>(t2);  \
        const bool lo = (l < (D));                                              \
        P00 = lo ? 1.0f : P00;                                                  \
        P11 = lo ? 1.0f : P11;                                                  \
        P22 = lo ? 1.0f : P22;                                                  \
        {                                                                       \
            float n00 = fmaf(P00,R00, fmaf(P01,R10, P02*R20));                  \
            float n01 = fmaf(P00,R01, fmaf(P01,R11, P02*R21));                  \
            float n02 = fmaf(P00,R02, fmaf(P01,R12, P02*R22));                  \
            float n10 = fmaf(P10,R00, fmaf(P11,R10, P12*R20));                  \
            float n11 = fmaf(P10,R01, fmaf(P11,R11, P12*R21));                  \
            float n12 = fmaf(P10,R02, fmaf(P11,R12, P12*R22));                  \
            float n20 = fmaf(P20,R00, fmaf(P21,R10, P22*R20));                  \
            float n21 = fmaf(P20,R01, fmaf(P21,R11, P22*R21));                  \
            float n22 = fmaf(P20,R02, fmaf(P21,R12, P22*R22));                  \
            float nt0 = fmaf(P00,t0, fmaf(P01,t1, fmaf(P02,t2, pt0)));          \
            float nt1 = fmaf(P10,t0, fmaf(P11,t1, fmaf(P12,t2, pt1)));          \
            float nt2 = fmaf(P20,t0, fmaf(P21,t1, fmaf(P22,t2, pt2)));          \
            R00=n00; R01=n01; R02=n02;                                          \
            R10=n10; R11=n11; R12=n12;                                          \
            R20=n20; R21=n21; R22=n22;                                          \
            t0=nt0; t1=nt1; t2=nt2;                                             \
        }                                                                       \
    }
    SCAN_STEP(1, DPP_SHR(1))
    SCAN_STEP(2, DPP_SHR(2))
    SCAN_STEP(4, DPP_SHR(4))
    SCAN_STEP(8, DPP_SHR(8))
    #undef SCAN_STEP

    // transform this lane's 4 spheres of link l straight to global ws
    float4* wsb = ws + (size_t)b * 128;
    #pragma unroll
    for (int k = 0; k < 4; ++k) {
        const int sp = g * 4 + k;
        float4 cs = reinterpret_cast<const float4*>(spheres)[l*8 + sp];
        float wx = fmaf(R00,cs.x, fmaf(R01,cs.y, fmaf(R02,cs.z, t0)));
        float wy = fmaf(R10,cs.x, fmaf(R11,cs.y, fmaf(R12,cs.z, t1)));
        float wz = fmaf(R20,cs.x, fmaf(R21,cs.y, fmaf(R22,cs.z, t2)));
        if (alive) wsb[l*8 + sp] = make_float4(wx, wy, wz, cs.w);
    }
}

// packed penetration: row sphere r vs column spheres of links (j, j+1)
__device__ __forceinline__ void pen2j(const float4& r,
                                      v2f px, v2f py, v2f pz, v2f pw,
                                      float& mi, float& mj1, float& mj2)
{
    v2f dx = px - r.x;
    v2f dy = py - r.y;
    v2f dz = pz - r.z;
    v2f d2 = dx * dx;
    d2 = __builtin_elementwise_fma(dy, dy, d2);
    d2 = __builtin_elementwise_fma(dz, dz, d2);
    v2f pen = (pw + r.w) - (v2f){__builtin_amdgcn_sqrtf(d2.x),
                                 __builtin_amdgcn_sqrtf(d2.y)};
    mi  = fmaxf(fmaxf(mi, pen.x), pen.y);   // v_max3_f32
    mj1 = fmaxf(mj1, pen.x);
    mj2 = fmaxf(mj2, pen.y);
}

__device__ __forceinline__ void pen1h(const float4& r,
                                      v2f px, v2f py, v2f pz, v2f pw,
                                      float& mi, float& mj)
{
    float dx = px.y - r.x, dy = py.y - r.y, dz = pz.y - r.z;
    float d2 = fmaf(dx, dx, fmaf(dy, dy, dz * dz));
    float p  = pw.y + r.w - __builtin_amdgcn_sqrtf(d2);
    mi = fmaxf(mi, p);
    mj = fmaxf(mj, p);
}

// ---------------------------------------------------------------------------
// K2: pair phase only, ONE batch per wave, (256,8) -> 8 waves/SIMD.
// With no FK in the function, the fenced named-scalar body (~45 live) should
// genuinely fit 64 VGPRs (R13 proved the fenced pair body fits even WITH FK).
// Stages 2KB/batch from ws into padded LDS (coalesced), then 4 fenced sweeps.
// ---------------------------------------------------------------------------
__global__ __launch_bounds__(256, 8) void pair_kernel(
    const float4* __restrict__ ws,      // [B,128]
    float* __restrict__ out,            // [B,16]
    int B)
{
    __shared__ float4 sph[4][16 * 9];
    const int t    = threadIdx.x;
    const int w    = t >> 6;
    const int lane = t & 63;
    int b = blockIdx.x * 4 + w;
    const bool alive = (b < B);
    if (!alive) b = B - 1;

    // ---- stage this wave's batch: 128 float4, coalesced (2 per lane)
    {
        const float4* src = ws + (size_t)b * 128;
        float4 v0 = src[lane];
        float4 v1 = src[lane + 64];
        sph[w][(lane >> 3) * 9 + (lane & 7)]        = v0;
        sph[w][((lane + 64) >> 3) * 9 + (lane & 7)] = v1;
    }
    asm volatile("s_waitcnt lgkmcnt(0)" ::: "memory");
    SCHED_FENCE();

    const float4* S  = sph[w];
    const float*  Sf = reinterpret_cast<const float*>(S);
    const int sr = lane >> 3;
    const int sc = lane & 7;
    const float4* Srow = S + sr;
    const float*  Scol = Sf + sc*4;

    float m0=-100.f,m1=-100.f,m2=-100.f,m3=-100.f,m4=-100.f,m5=-100.f,
          m6=-100.f,m7=-100.f,m8=-100.f,m9=-100.f,m10=-100.f,m11=-100.f,
          m12=-100.f,m13=-100.f,m14=-100.f,m15=-100.f;

    v2f Ax,Ay,Az,Aw, Bx,By,Bz,Bw;

    #define FILLP(Px,Py,Pz,Pw, j)                                               \
    {                                                                           \
        Px = (v2f){Scol[(j)*36+0], Scol[(j)*36+36]};                            \
        Py = (v2f){Scol[(j)*36+1], Scol[(j)*36+37]};                            \
        Pz = (v2f){Scol[(j)*36+2], Scol[(j)*36+38]};                            \
        Pw = (v2f){Scol[(j)*36+3], Scol[(j)*36+39]};                            \
    }

    // sweep 1: packs A=(2,3), B=(4,5); rows 0..3
    FILLP(Ax,Ay,Az,Aw, 2)
    FILLP(Bx,By,Bz,Bw, 4)
    { float4 r = Srow[0*9]; pen2j(r,Ax,Ay,Az,Aw, m0,m2,m3); pen2j(r,Bx,By,Bz,Bw, m0,m4,m5); }
    { float4 r = Srow[1*9]; pen1h(r,Ax,Ay,Az,Aw, m1,m3);    pen2j(r,Bx,By,Bz,Bw, m1,m4,m5); }
    { float4 r = Srow[2*9]; pen2j(r,Bx,By,Bz,Bw, m2,m4,m5); }
    { float4 r = Srow[3*9]; pen1h(r,Bx,By,Bz,Bw, m3,m5); }
    SCHED_FENCE();

    // sweep 2: packs A=(6,7), B=(8,9); rows 0..7
    FILLP(Ax,Ay,Az,Aw, 6)
    FILLP(Bx,By,Bz,Bw, 8)
    { float4 r = Srow[0*9]; pen2j(r,Ax,Ay,Az,Aw, m0,m6,m7); pen2j(r,Bx,By,Bz,Bw, m0,m8,m9); }
    { float4 r = Srow[1*9]; pen2j(r,Ax,Ay,Az,Aw, m1,m6,m7); pen2j(r,Bx,By,Bz,Bw, m1,m8,m9); }
    { float4 r = Srow[2*9]; pen2j(r,Ax,Ay,Az,Aw, m2,m6,m7); pen2j(r,Bx,By,Bz,Bw, m2,m8,m9); }
    { float4 r = Srow[3*9]; pen2j(r,Ax,Ay,Az,Aw, m3,m6,m7); pen2j(r,Bx,By,Bz,Bw, m3,m8,m9); }
    { float4 r = Srow[4*9]; pen2j(r,Ax,Ay,Az,Aw, m4,m6,m7); pen2j(r,Bx,By,Bz,Bw, m4,m8,m9); }
    { float4 r = Srow[5*9]; pen1h(r,Ax,Ay,Az,Aw, m5,m7);    pen2j(r,Bx,By,Bz,Bw, m5,m8,m9); }
    { float4 r = Srow[6*9]; pen2j(r,Bx,By,Bz,Bw, m6,m8,m9); }
    { float4 r = Srow[7*9]; pen1h(r,Bx,By,Bz,Bw, m7,m9); }
    SCHED_FENCE();

    // sweep 3: packs A=(10,11), B=(12,13); rows 0..11
    FILLP(Ax,Ay,Az,Aw, 10)
    FILLP(Bx,By,Bz,Bw, 12)
    { float4 r = Srow[0*9];  pen2j(r,Ax,Ay,Az,Aw, m0,m10,m11); pen2j(r,Bx,By,Bz,Bw, m0,m12,m13); }
    { float4 r = Srow[1*9];  pen2j(r,Ax,Ay,Az,Aw, m1,m10,m11); pen2j(r,Bx,By,Bz,Bw, m1,m12,m13); }
    { float4 r = Srow[2*9];  pen2j(r,Ax,Ay,Az,Aw, m2,m10,m11); pen2j(r,Bx,By,Bz,Bw, m2,m12,m13); }
    { float4 r = Srow[3*9];  pen2j(r,Ax,Ay,Az,Aw, m3,m10,m11); pen2j(r,Bx,By,Bz,Bw, m3,m12,m13); }
    { float4 r = Srow[4*9];  pen2j(r,Ax,Ay,Az,Aw, m4,m10,m11); pen2j(r,Bx,By,Bz,Bw, m4,m12,m13); }
    { float4 r = Srow[5*9];  pen2j(r,Ax,Ay,Az,Aw, m5,m10,m11); pen2j(r,Bx,By,Bz,Bw, m5,m12,m13); }
    { float4 r = Srow[6*9];  pen2j(r,Ax,Ay,Az,Aw, m6,m10,m11); pen2j(r,Bx,By,Bz,Bw, m6,m12,m13); }
    { float4 r = Srow[7*9];  pen2j(r,Ax,Ay,Az,Aw, m7,m10,m11); pen2j(r,Bx,By,Bz,Bw, m7,m12,m13); }
    { float4 r = Srow[8*9];  pen2j(r,Ax,Ay,Az,Aw, m8,m10,m11); pen2j(r,Bx,By,Bz,Bw, m8,m12,m13); }
    { float4 r = Srow[9*9];  pen1h(r,Ax,Ay,Az,Aw, m9,m11);     pen2j(r,Bx,By,Bz,Bw, m9,m12,m13); }
    { float4 r = Srow[10*9]; pen2j(r,Bx,By,Bz,Bw, m10,m12,m13); }
    { float4 r = Srow[11*9]; pen1h(r,Bx,By,Bz,Bw, m11,m13); }
    SCHED_FENCE();

    // sweep 4: pack A=(14,15); rows 0..13
    FILLP(Ax,Ay,Az,Aw, 14)
    { float4 r = Srow[0*9];  pen2j(r,Ax,Ay,Az,Aw, m0,m14,m15); }
    { float4 r = Srow[1*9];  pen2j(r,Ax,Ay,Az,Aw, m1,m14,m15); }
    { float4 r = Srow[2*9];  pen2j(r,Ax,Ay,Az,Aw, m2,m14,m15); }
    { float4 r = Srow[3*9];  pen2j(r,Ax,Ay,Az,Aw, m3,m14,m15); }
    { float4 r = Srow[4*9];  pen2j(r,Ax,Ay,Az,Aw, m4,m14,m15); }
    { float4 r = Srow[5*9];  pen2j(r,Ax,Ay,Az,Aw, m5,m14,m15); }
    { float4 r = Srow[6*9];  pen2j(r,Ax,Ay,Az,Aw, m6,m14,m15); }
    { float4 r = Srow[7*9];  pen2j(r,Ax,Ay,Az,Aw, m7,m14,m15); }
    { float4 r = Srow[8*9];  pen2j(r,Ax,Ay,Az,Aw, m8,m14,m15); }
    { float4 r = Srow[9*9];  pen2j(r,Ax,Ay,Az,Aw, m9,m14,m15); }
    { float4 r = Srow[10*9]; pen2j(r,Ax,Ay,Az,Aw, m10,m14,m15); }
    { float4 r = Srow[11*9]; pen2j(r,Ax,Ay,Az,Aw, m11,m14,m15); }
    { float4 r = Srow[12*9]; pen2j(r,Ax,Ay,Az,Aw, m12,m14,m15); }
    { float4 r = Srow[13*9]; pen1h(r,Ax,Ay,Az,Aw, m13,m15); }
    #undef FILLP
    SCHED_FENCE();

    // ---- log-fold wave reduction, named scalars (13 DPP + 4 shfl)
    {
        const int bit0 = lane & 1;
        #define F1(A,C) { float s_ = bit0 ? A : C; float r_ = dppmov<DPP_XOR1>(s_); A = fmaxf(bit0 ? C : A, r_); }
        F1(m0,m8) F1(m1,m9) F1(m2,m10) F1(m3,m11) F1(m4,m12) F1(m5,m13) F1(m6,m14) F1(m7,m15)
        #undef F1
        const int bit1 = (lane >> 1) & 1;
        #define F2(A,C) { float s_ = bit1 ? A : C; float r_ = dppmov<DPP_XOR2>(s_); A = fmaxf(bit1 ? C : A, r_); }
        F2(m0,m4) F2(m1,m5) F2(m2,m6) F2(m3,m7)
        #undef F2
        const int bit2 = (lane >> 2) & 1;
        #define F4(A,C) { float s_ = bit2 ? A : C; float r_ = __shfl_xor(s_, 4, 64); A = fmaxf(bit2 ? C : A, r_); }
        F4(m0,m2) F4(m1,m3)
        #undef F4
        const int bit3 = (lane >> 3) & 1;
        { float s_ = bit3 ? m0 : m1; float r_ = dppmov<DPP_XOR8>(s_); m0 = fmaxf(bit3 ? m1 : m0, r_); }
        m0 = fmaxf(m0, __shfl_xor(m0, 16, 64));
        m0 = fmaxf(m0, __shfl_xor(m0, 32, 64));
    }

    if (alive && lane < 16) {
        int k = ((lane & 1) << 3) | ((lane & 2) << 1) | ((lane & 4) >> 1) | ((lane & 8) >> 3);
        out[(size_t)b * 16 + k] = m0;
    }
}

// ---------------------------------------------------------------------------
extern "C" void kernel_launch(void* const* d_in, const int* in_sizes, int n_in,
                              void* d_out, int out_size, void* d_ws, size_t ws_size,
                              hipStream_t stream) {
    const float* q      = (const float*)d_in[0];
    const float* frot   = (const float*)d_in[1];
    const float* ftrans = (const float*)d_in[2];
    const float* axes   = (const float*)d_in[3];
    const float* sphere = (const float*)d_in[4];
    float* out = (float*)d_out;

    const int B = in_sizes[0] / 16;
    // ws usage: B*128 float4 = 16 MB (harness workspace is large enough; if
    // not, fall back would be needed — B=8192 -> 16 MB, standard ws size).
    fk_kernel<<<dim3((B + 7) / 8), dim3(256), 0, stream>>>(
        q, frot, ftrans, axes, sphere, (float4*)d_ws, B);
    pair_kernel<<<dim3((B + 3) / 4), dim3(256), 0, stream>>>(
        (const float4*)d_ws, out, B);
}

// Round 16
// 19.920 us; speedup vs baseline: 2.7072x; 1.7175x over previous
//
#include <hip/hip_runtime.h>

typedef float v2f __attribute__((ext_vector_type(2)));

// compile-time DPP move: dest lane gets src lane per CTRL pattern.
// bound_ctrl=true: lanes whose source falls outside the 16-lane row read 0.
// NOTE: execute with source lanes ACTIVE (EXEC-disabled sources read 0).
template<int CTRL>
__device__ __forceinline__ float dppmov(float x) {
    return __builtin_bit_cast(float,
        __builtin_amdgcn_update_dpp(0, __builtin_bit_cast(int, x),
                                    CTRL, 0xf, 0xf, true));
}
#define DPP_XOR1  0xB1   // quad_perm [1,0,3,2]
#define DPP_XOR2  0x4E   // quad_perm [2,3,0,1]
#define DPP_XOR8  0x128  // row_ror:8 == lane^8 within 16-lane rows
#define DPP_SHR(d) (0x110 | (d))

// packed penetration: one row sphere vs packed column spheres {sc2, sc2+4}
// of the SAME link j -> both maxes fold with v_max3.
__device__ __forceinline__ void pen2p(const float4& rs,
                                      v2f cx, v2f cy, v2f cz, v2f cw,
                                      float& mi, float& mj)
{
    v2f dx = cx - rs.x;
    v2f dy = cy - rs.y;
    v2f dz = cz - rs.z;
    v2f d2 = dx * dx;
    d2 = __builtin_elementwise_fma(dy, dy, d2);
    d2 = __builtin_elementwise_fma(dz, dz, d2);
    v2f pen = (cw + rs.w) - (v2f){__builtin_amdgcn_sqrtf(d2.x),
                                  __builtin_amdgcn_sqrtf(d2.y)};
    mi = fmaxf(fmaxf(mi, pen.x), pen.y);   // v_max3_f32
    mj = fmaxf(fmaxf(mj, pen.x), pen.y);   // v_max3_f32
}

// ---- 3-column register tile: fill + compute, all indices compile-time ----
template<int JLO, int JHI>
__device__ __forceinline__ void fill_tile(v2f (&cx)[3], v2f (&cy)[3],
                                          v2f (&cz)[3], v2f (&cw)[3],
                                          const float* __restrict__ Sf, int sc2)
{
    #pragma unroll
    for (int j = JLO; j <= JHI; ++j) {
        const int bd = j*36 + sc2*4;
        cx[j-JLO] = (v2f){Sf[bd+0], Sf[bd+16]};
        cy[j-JLO] = (v2f){Sf[bd+1], Sf[bd+17]};
        cz[j-JLO] = (v2f){Sf[bd+2], Sf[bd+18]};
        cw[j-JLO] = (v2f){Sf[bd+3], Sf[bd+19]};
    }
}

template<int JLO, int JHI>
__device__ __forceinline__ void compute_tile(const v2f (&cx)[3], const v2f (&cy)[3],
                                             const v2f (&cz)[3], const v2f (&cw)[3],
                                             const float4* __restrict__ S,
                                             int sr, float (&m)[16])
{
    constexpr int IMAX = (JHI - 2 < 13) ? (JHI - 2) : 13;
    #pragma unroll
    for (int i = 0; i <= IMAX; ++i) {
        float4 rs = S[i*9 + sr];
        const int j0 = (i + 2 > JLO) ? (i + 2) : JLO;
        #pragma unroll
        for (int j = JLO; j <= JHI; ++j) {
            if (j < j0) continue;   // compile-time after unroll
            pen2p(rs, cx[j-JLO], cy[j-JLO], cz[j-JLO], cw[j-JLO], m[i], m[j]);
        }
    }
}

// ---------------------------------------------------------------------------
// Fully fused, TWO batches per wave (lanes 0-31 batch A, 32-63 batch B).
// 128-reg tier. This is the measured optimum of the explored design space:
//  - 8-wave tier (<=64 VGPR) is allocator-infeasible for this body: caps force
//    wholesale scratch demotion (R6/R9/R12/R14: 150+ MB scratch, 2-3x slower);
//    full sched-fencing fits but over-serializes (R13: 23.7us); split kernels
//    don't help (R15: 34.2us).
//  - FK prefix product via DPP row_shr, branchless (P diag forced to 1 for
//    lanes l<D; bound_ctrl zeros make those lanes compute an exact no-op).
//  - Each lane transforms 4 spheres of its link into padded LDS (stride 9).
//  - Pair phase: 32 lanes per batch; lane owns (row sr = L>>2, cols {sc2,sc2+4});
//    5 software-pipelined 3-column tiles, double-buffered (A/B).
//  - Per-link max: log-fold, 13 DPP + 2 shfl + xor16 merge.
// ---------------------------------------------------------------------------
__global__ __launch_bounds__(256, 4) void fused_kernel(
    const float* __restrict__ q,        // [B,16]
    const float* __restrict__ frot,     // [16,3,3]
    const float* __restrict__ ftrans,   // [16,3]
    const float* __restrict__ axes,     // [16,3]
    const float* __restrict__ spheres,  // [16,8,4]
    float* __restrict__ out,            // [B,16]
    int B)
{
    __shared__ float4 sph[4][2][16 * 9];   // [wave][batch-half][link*9 + sphere]
    const int t    = threadIdx.x;
    const int w    = t >> 6;
    const int lane = t & 63;
    const int h    = lane >> 5;            // batch half within wave
    int b = blockIdx.x * 8 + w * 2 + h;
    const bool alive = (b < B);
    if (!alive) b = B - 1;

    const int l = lane & 15;               // link this lane owns in FK phase
    const int g = (lane >> 4) & 1;         // sphere-group (4 spheres each)

    // ---- local joint transform: R = F * J(axis,q)
    const float qv = q[(size_t)b * 16 + l];
    const float s = __sinf(qv), c = __cosf(qv), oc = 1.0f - c;
    const float ax = axes[3*l+0], ay = axes[3*l+1], az = axes[3*l+2];

    const float F00=frot[9*l+0], F01=frot[9*l+1], F02=frot[9*l+2];
    const float F10=frot[9*l+3], F11=frot[9*l+4], F12=frot[9*l+5];
    const float F20=frot[9*l+6], F21=frot[9*l+7], F22=frot[9*l+8];

    float R00,R01,R02,R10,R11,R12,R20,R21,R22;
    {
        float u0 = fmaf(F01,az, -F02*ay);
        float u1 = fmaf(F02,ax, -F00*az);
        float u2 = fmaf(F00,ay, -F01*ax);
        float v0 = fmaf(u1,az, -u2*ay);
        float v1 = fmaf(u2,ax, -u0*az);
        float v2 = fmaf(u0,ay, -u1*ax);
        R00 = fmaf(oc,v0, fmaf(s,u0, F00));
        R01 = fmaf(oc,v1, fmaf(s,u1, F01));
        R02 = fmaf(oc,v2, fmaf(s,u2, F02));

        u0 = fmaf(F11,az, -F12*ay);
        u1 = fmaf(F12,ax, -F10*az);
        u2 = fmaf(F10,ay, -F11*ax);
        v0 = fmaf(u1,az, -u2*ay);
        v1 = fmaf(u2,ax, -u0*az);
        v2 = fmaf(u0,ay, -u1*ax);
        R10 = fmaf(oc,v0, fmaf(s,u0, F10));
        R11 = fmaf(oc,v1, fmaf(s,u1, F11));
        R12 = fmaf(oc,v2, fmaf(s,u2, F12));

        u0 = fmaf(F21,az, -F22*ay);
        u1 = fmaf(F22,ax, -F20*az);
        u2 = fmaf(F20,ay, -F21*ax);
        v0 = fmaf(u1,az, -u2*ay);
        v1 = fmaf(u2,ax, -u0*az);
        v2 = fmaf(u0,ay, -u1*ax);
        R20 = fmaf(oc,v0, fmaf(s,u0, F20));
        R21 = fmaf(oc,v1, fmaf(s,u1, F21));
        R22 = fmaf(oc,v2, fmaf(s,u2, F22));
    }
    float t0 = ftrans[3*l+0], t1 = ftrans[3*l+1], t2 = ftrans[3*l+2];

    // ---- branchless Kogge-Stone prefix product over width-16 segments
    #define SCAN_STEP(D, CTRL)                                                  \
    {                                                                           \
        float P00 = dppmov<CTRL>(R00), P01 = dppmov<CTRL>(R01), P02 = dppmov<CTRL>(R02); \
        float P10 = dppmov<CTRL>(R10), P11 = dppmov<CTRL>(R11), P12 = dppmov<CTRL>(R12); \
        float P20 = dppmov<CTRL>(R20), P21 = dppmov<CTRL>(R21), P22 = dppmov<CTRL>(R22); \
        float pt0 = dppmov<CTRL>(t0),  pt1 = dppmov<CTRL>(t1),  pt2 = dppmov<CTRL>(t2);  \
        const bool lo = (l < (D));      /* P,pt are 0 here (bound_ctrl) */      \
        P00 = lo ? 1.0f : P00;                                                  \
        P11 = lo ? 1.0f : P11;                                                  \
        P22 = lo ? 1.0f : P22;          /* P = I for lo lanes -> exact no-op */ \
        {                                                                       \
            float n00 = fmaf(P00,R00, fmaf(P01,R10, P02*R20));                  \
            float n01 = fmaf(P00,R01, fmaf(P01,R11, P02*R21));                  \
            float n02 = fmaf(P00,R02, fmaf(P01,R12, P02*R22));                  \
            float n10 = fmaf(P10,R00, fmaf(P11,R10, P12*R20));                  \
            float n11 = fmaf(P10,R01, fmaf(P11,R11, P12*R21));                  \
            float n12 = fmaf(P10,R02, fmaf(P11,R12, P12*R22));                  \
            float n20 = fmaf(P20,R00, fmaf(P21,R10, P22*R20));                  \
            float n21 = fmaf(P20,R01, fmaf(P21,R11, P22*R21));                  \
            float n22 = fmaf(P20,R02, fmaf(P21,R12, P22*R22));                  \
            float nt0 = fmaf(P00,t0, fmaf(P01,t1, fmaf(P02,t2, pt0)));          \
            float nt1 = fmaf(P10,t0, fmaf(P11,t1, fmaf(P12,t2, pt1)));          \
            float nt2 = fmaf(P20,t0, fmaf(P21,t1, fmaf(P22,t2, pt2)));          \
            R00=n00; R01=n01; R02=n02;                                          \
            R10=n10; R11=n11; R12=n12;                                          \
            R20=n20; R21=n21; R22=n22;                                          \
            t0=nt0; t1=nt1; t2=nt2;                                             \
        }                                                                       \
    }
    SCAN_STEP(1, DPP_SHR(1))
    SCAN_STEP(2, DPP_SHR(2))
    SCAN_STEP(4, DPP_SHR(4))
    SCAN_STEP(8, DPP_SHR(8))
    #undef SCAN_STEP

    // ---- transform this lane's 4 spheres of link l into padded LDS
    #pragma unroll
    for (int k = 0; k < 4; ++k) {
        const int sp = g * 4 + k;
        float4 cs = reinterpret_cast<const float4*>(spheres)[l*8 + sp];
        float wx = fmaf(R00,cs.x, fmaf(R01,cs.y, fmaf(R02,cs.z, t0)));
        float wy = fmaf(R10,cs.x, fmaf(R11,cs.y, fmaf(R12,cs.z, t1)));
        float wz = fmaf(R20,cs.x, fmaf(R21,cs.y, fmaf(R22,cs.z, t2)));
        sph[w][h][l*9 + sp] = make_float4(wx, wy, wz, cs.w);
    }
    // wave-private LDS region: just drain this wave's writes, no barrier
    asm volatile("s_waitcnt lgkmcnt(0)" ::: "memory");

    // ---- pairwise penetration, per-link max (32 lanes per batch)
    const float4* S  = sph[w][h];
    const float*  Sf = reinterpret_cast<const float*>(S);
    const int L   = lane & 31;
    const int sr  = L >> 2;        // row sphere 0..7
    const int sc2 = L & 3;         // column spheres {sc2, sc2+4}

    float m[16];
    #pragma unroll
    for (int k = 0; k < 16; ++k) m[k] = -100.0f;

    // ---- 5 software-pipelined 3-column tiles, double-buffered A/B.
    {
        v2f Acx[3], Acy[3], Acz[3], Acw[3];
        v2f Bcx[3], Bcy[3], Bcz[3], Bcw[3];

        fill_tile<2,4>  (Acx,Acy,Acz,Acw, Sf, sc2);
        fill_tile<5,7>  (Bcx,Bcy,Bcz,Bcw, Sf, sc2);
        compute_tile<2,4>  (Acx,Acy,Acz,Acw, S, sr, m);
        fill_tile<8,10> (Acx,Acy,Acz,Acw, Sf, sc2);
        compute_tile<5,7>  (Bcx,Bcy,Bcz,Bcw, S, sr, m);
        fill_tile<11,13>(Bcx,Bcy,Bcz,Bcw, Sf, sc2);
        compute_tile<8,10> (Acx,Acy,Acz,Acw, S, sr, m);
        fill_tile<14,15>(Acx,Acy,Acz,Acw, Sf, sc2);
        compute_tile<11,13>(Bcx,Bcy,Bcz,Bcw, S, sr, m);
        compute_tile<14,15>(Acx,Acy,Acz,Acw, S, sr, m);
    }

    // ---- log-fold reduction over the 32 lanes of this batch half
    {
        int bit0 = lane & 1;
        #pragma unroll
        for (int k = 0; k < 8; ++k) {
            float send = bit0 ? m[k] : m[k+8];
            float recv = dppmov<DPP_XOR1>(send);
            m[k] = fmaxf(bit0 ? m[k+8] : m[k], recv);
        }
        int bit1 = (lane >> 1) & 1;
        #pragma unroll
        for (int k = 0; k < 4; ++k) {
            float send = bit1 ? m[k] : m[k+4];
            float recv = dppmov<DPP_XOR2>(send);
            m[k] = fmaxf(bit1 ? m[k+4] : m[k], recv);
        }
        int bit2 = (lane >> 2) & 1;
        #pragma unroll
        for (int k = 0; k < 2; ++k) {
            float send = bit2 ? m[k] : m[k+2];
            float recv = __shfl_xor(send, 4, 64);
            m[k] = fmaxf(bit2 ? m[k+2] : m[k], recv);
        }
        int bit3 = (lane >> 3) & 1;
        {
            float send = bit3 ? m[0] : m[1];
            float recv = dppmov<DPP_XOR8>(send);
            m[0] = fmaxf(bit3 ? m[1] : m[0], recv);
        }
        // merge the two 16-lane groups of this batch half
        float v = m[0];
        v = fmaxf(v, __shfl_xor(v, 16, 64));
        m[0] = v;
    }

    if (alive && (lane & 16) == 0) {
        // link index = bit-reversal of lane's low 4 bits
        int k = ((lane & 1) << 3) | ((lane & 2) << 1) | ((lane & 4) >> 1) | ((lane & 8) >> 3);
        out[(size_t)b * 16 + k] = m[0];
    }
}

// ---------------------------------------------------------------------------
extern "C" void kernel_launch(void* const* d_in, const int* in_sizes, int n_in,
                              void* d_out, int out_size, void* d_ws, size_t ws_size,
                              hipStream_t stream) {
    const float* q      = (const float*)d_in[0];
    const float* frot   = (const float*)d_in[1];
    const float* ftrans = (const float*)d_in[2];
    const float* axes   = (const float*)d_in[3];
    const float* sphere = (const float*)d_in[4];
    float* out = (float*)d_out;

    const int B = in_sizes[0] / 16;
    const int blocks = (B + 7) / 8;     // 2 batches per wave, 8 per block
    fused_kernel<<<dim3(blocks), dim3(256), 0, stream>>>(
        q, frot, ftrans, axes, sphere, out, B);
}